// Round 8
// baseline (3453.674 us; speedup 1.0000x reference)
//
#include <hip/hip_runtime.h>

#define T_TOK 8192   // B*S tokens
#define DIM   768
#define NCB   8192   // codebook entries
#define KSEL  8
#define K12   12     // candidates kept per token (filter)
#define NSPLIT 16
#define BT    128    // tokens per filter block (2 per lane)
#define CTILE 32     // codes per block tile (8 per wave)
#define BD    32     // d-chunk staged in LDS
#define NTILE ((NCB/NSPLIT)/CTILE)   // 16
// margin: |fma-any-order - numpy-order| <= 2*gamma768*sqrt(x2*c2) per side;
// gamma768 = 768*2^-24 = 4.58e-5. K1 = 4e-4 (~5x slack), K2 absorbs the
// combine roundings (~5e-4).
#define MARG_K1 4.0e-4f
#define MARG_K2 2.0e-3f

typedef float v16f __attribute__((ext_vector_type(16)));

// 16B global->LDS DMA. Dest is wave-uniform base + lane*16 (HW rule).
__device__ __forceinline__ void gload16(const float* g, float4* l) {
  __builtin_amdgcn_global_load_lds(
      (const __attribute__((address_space(1))) void*)g,
      (__attribute__((address_space(3))) void*)l, 16, 0, 0);
}

// two s_load_dwordx16: 32 floats (one code's 32-d chunk) into SGPRs [R6-proven]
#define SLOAD(d0_, d1_, ap)                                                  \
  asm volatile("s_load_dwordx16 %0, %2, 0x0\n\t"                             \
               "s_load_dwordx16 %1, %2, 0x40"                                \
               : "=s"(d0_), "=s"(d1_) : "s"(ap));

// wait-all, and PIN the buffers: "+s" makes every later use of d0_/d1_
// data-depend on this asm, so C-level FMAs cannot be hoisted above the wait.
#define WAITP(d0_, d1_)                                                      \
  asm volatile("s_waitcnt lgkmcnt(0)" : "+s"(d0_), "+s"(d1_) :: "memory");

// one code j, both tokens, 32 dims: 64 FMAs (free order, contract=on)
#define MACJ(j_, C0_, C1_)                                                   \
  { _Pragma("unroll")                                                        \
    for (int q_ = 0; q_ < 8; ++q_) {                                         \
      const float4 xu_ = xa[q_], xv_ = xc[q_];                               \
      _Pragma("unroll")                                                      \
      for (int e_ = 0; e_ < 4; ++e_) {                                       \
        const float cv_ = (q_ < 4) ? C0_[q_*4+e_] : C1_[(q_-4)*4+e_];        \
        const float x0_ = e_==0?xu_.x:e_==1?xu_.y:e_==2?xu_.z:xu_.w;         \
        const float x1_ = e_==0?xv_.x:e_==1?xv_.y:e_==2?xv_.z:xv_.w;         \
        a0[j_] += x0_ * cv_;                                                 \
        a1[j_] += x1_ * cv_;                                                 \
      } } }

// ---------------------------------------------------------------------------
// Kernel A: ||row||^2 — bit-exact modern-numpy pairwise_sum (npyv/AVX-512
// W=16) over t[k]=fl32(v*v). [frozen — do not change rounding]
// Norms go to ws; also atomicMax of c2 (float>0 => uint bit order == float
// order) for the margin bound.
// ---------------------------------------------------------------------------
__global__ __launch_bounds__(256) void sq_pairwise_kernel(
    const float* __restrict__ cb, const float* __restrict__ x,
    float* __restrict__ c2out, float* __restrict__ x2out,
    unsigned int* __restrict__ c2max)
{
  #pragma clang fp contract(off)
  __shared__ float part[32][8];
  const int tid = threadIdx.x;
  const int row = blockIdx.x * 32 + (tid >> 3);       // 0..16383
  const int b   = tid & 7;                            // 96-block index
  const float* src = (row < NCB) ? (cb + (size_t)row * DIM)
                                 : (x + (size_t)(row - NCB) * DIM);
  const float* a = src + 96 * b;

  float s[16];
  #pragma unroll
  for (int l = 0; l < 16; ++l) {
    float v, t;
    v = a[l];       t = v * v; float r0 = t;
    v = a[64 + l];  t = v * v; r0 = r0 + t;
    v = a[80 + l];  t = v * v; r0 = r0 + t;
    v = a[16 + l];  t = v * v; float r1 = t;
    v = a[32 + l];  t = v * v; float r2 = t;
    v = a[48 + l];  t = v * v; float r3 = t;
    s[l] = (r0 + r1) + (r2 + r3);
  }
  float t1[8], t2[4];
  #pragma unroll
  for (int i = 0; i < 8; ++i) t1[i] = s[i] + s[i + 8];
  #pragma unroll
  for (int j = 0; j < 4; ++j) t2[j] = t1[j] + t1[j + 4];
  part[tid >> 3][b] = (t2[0] + t2[2]) + (t2[1] + t2[3]);
  __syncthreads();

  if (b == 0) {
    const float* p = part[tid >> 3];
    float res = ((p[0] + p[1]) + (p[2] + p[3])) + ((p[4] + p[5]) + (p[6] + p[7]));
    if (row < NCB) {
      c2out[row] = res;
      atomicMax(c2max, __float_as_uint(res));
    } else {
      x2out[row - NCB] = res;
    }
  }
}

// ---------------------------------------------------------------------------
// Kernel B: FILTER — fp32 FMA (free order) distances, per-split approx top-12.
// R6's proven SMEM/SGPR c-path (scalar address via readfirstlane — the R7
// compile fix) + LDS x staging, 2 tokens/thread (BT=128): MAC work per SMEM
// wait doubles vs R6 (64 fmac), chunks halve => half the wait-all stalls.
// Top-12 per token lives in LDS; insertion is wave-phased (w==p) so exactly
// one thread touches a token's state per phase (no races). Exactness is NOT
// required here — completeness is guaranteed by the margin check in merge12
// + the frozen recompute in the exact pass.
// ---------------------------------------------------------------------------
__global__ __launch_bounds__(256, 3) void filt_topk_kernel(
    const float* __restrict__ x, const float* __restrict__ cb,
    const float* __restrict__ c2g, const float* __restrict__ x2g,
    float* __restrict__ p1out)
{
  __shared__ float4 sbuf[2048];        // 2 bufs x [8 quads][128 tok] = 32768 B
  __shared__ float  bd[BT][K12];       // 6144 B
  __shared__ int    bi[BT][K12];       // 6144 B
  __shared__ float  bmx[BT];           // 512 B

  const int tid  = threadIdx.x;
  const int t0   = blockIdx.x * BT;
  const int nbeg = blockIdx.y * (NCB / NSPLIT);
  const int lane = tid & 63;
  const int w    = tid >> 6;
  const int wS   = __builtin_amdgcn_readfirstlane(w);   // uniform copy (SGPR)

  for (int i = tid; i < BT; i += 256) bmx[i] = __builtin_inff();
  for (int i = tid; i < BT * K12; i += 256) {
    ((float*)bd)[i] = __builtin_inff();
    ((int*)bi)[i]   = 0x7fffffff;
  }

  // x DMA: call k stages slot (tid + k*256) of [q][t]: q=(w>>1)+2k, t=(w&1)*64+lane
  const float* xsrc = x + (size_t)(t0 + (w & 1) * 64 + lane) * DIM + (w >> 1) * 4;
  float4* xdst = sbuf + tid;           // + buf*1024 + k*256

  const float x2a = x2g[t0 + lane];
  const float x2b = x2g[t0 + 64 + lane];

  for (int tile = 0; tile < NTILE; ++tile) {
    const int n0 = nbeg + tile * CTILE;
    float a0[8], a1[8];
    #pragma unroll
    for (int j = 0; j < 8; ++j) { a0[j] = 0.f; a1[j] = 0.f; }

    // byte base of this wave's 8 codes (scalar/uniform address!)
    const uint64_t cbT = (uint64_t)(uintptr_t)cb
                       + (uint64_t)(n0 + wS * 8) * (DIM * 4);

    __syncthreads();                   // state phase done / prev tile reads done
    #pragma unroll
    for (int k = 0; k < 4; ++k) gload16(xsrc + k * 8, xdst + k * 256);
    __syncthreads();                   // chunk 0 visible

    for (int d0 = 0; d0 < DIM; d0 += BD) {
      const int buf = (d0 >> 5) & 1;
      const int dn = d0 + BD;
      if (dn < DIM) {
        float4* nb = xdst + (buf ^ 1) * 1024;
        #pragma unroll
        for (int k = 0; k < 4; ++k) gload16(xsrc + dn + k * 8, nb + k * 256);
      }

      // preload both tokens' 8 quads (2-way bank aliasing = free)
      const float4* xb = sbuf + buf * 1024;
      float4 xa[8], xc[8];
      #pragma unroll
      for (int q = 0; q < 8; ++q) {
        xa[q] = xb[q * 128 + lane];
        xc[q] = xb[q * 128 + 64 + lane];
      }

      const uint64_t ca = cbT + (uint64_t)d0 * 4;
      v16f A0, A1, B0, B1;
      SLOAD(A0, A1, ca)
      WAITP(A0, A1)
      SLOAD(B0, B1, ca + 1 * 3072)  MACJ(0, A0, A1) WAITP(B0, B1)
      SLOAD(A0, A1, ca + 2 * 3072)  MACJ(1, B0, B1) WAITP(A0, A1)
      SLOAD(B0, B1, ca + 3 * 3072)  MACJ(2, A0, A1) WAITP(B0, B1)
      SLOAD(A0, A1, ca + 4 * 3072)  MACJ(3, B0, B1) WAITP(A0, A1)
      SLOAD(B0, B1, ca + 5 * 3072)  MACJ(4, A0, A1) WAITP(B0, B1)
      SLOAD(A0, A1, ca + 6 * 3072)  MACJ(5, B0, B1) WAITP(A0, A1)
      SLOAD(B0, B1, ca + 7 * 3072)  MACJ(6, A0, A1) WAITP(B0, B1)
      MACJ(7, B0, B1)

      __syncthreads();                 // reads done + next-chunk DMA landed
    }

    // ---- approx distances + wave-phased LDS top-12 insertion ----
    float dd0[8], dd1[8];
    #pragma unroll
    for (int j = 0; j < 8; ++j) {
      const float c2 = c2g[n0 + w * 8 + j];
      const float s0 = 2.0f * a0[j] - x2a;
      const float s1 = 2.0f * a1[j] - x2b;
      dd0[j] = -(s0 - c2);
      dd1[j] = -(s1 - c2);
    }
    const int idb = n0 + w * 8;
    #pragma unroll 1
    for (int p = 0; p < 4; ++p) {
      if (w == p) {
        #pragma unroll 1
        for (int h = 0; h < 2; ++h) {
          const int tl = h * 64 + lane;
          float bm = bmx[tl];
          #pragma unroll 1
          for (int j = 0; j < 8; ++j) {
            const float d = h ? dd1[j] : dd0[j];
            if (d < bm) {
              int ms = 0; float mv = bd[tl][0];
              for (int k = 1; k < K12; ++k) {
                const float v = bd[tl][k];
                if (v > mv) { mv = v; ms = k; }
              }
              bd[tl][ms] = d; bi[tl][ms] = idb + j;
              bm = bd[tl][0];
              for (int k = 1; k < K12; ++k) bm = fmaxf(bm, bd[tl][k]);
            }
          }
          bmx[tl] = bm;
        }
      }
      __syncthreads();
    }
  }

  // ---- write this split's top-12 (dist + id) per token ----
  const int tt = tid & 127, hh = tid >> 7;
  const size_t ob = ((size_t)blockIdx.y * T_TOK + (t0 + tt)) * 24;
  #pragma unroll
  for (int k = 0; k < 6; ++k) {
    p1out[ob + hh * 6 + k] = bd[tt][hh * 6 + k];
    ((int*)p1out)[ob + 12 + hh * 6 + k] = bi[tt][hh * 6 + k];
  }
}

// ---------------------------------------------------------------------------
// Kernel C: merge NSPLIT x 12 approx candidates -> global approx top-12 per
// token; check completeness condition a12 > a8 + 2m (margin m from norms).
// flag!=0 => fall back to a full frozen rescan for this token in the exact
// pass (expected: never).
// ---------------------------------------------------------------------------
__global__ __launch_bounds__(64) void merge12_kernel(
    const float* __restrict__ p1, const float* __restrict__ x2g,
    const float* __restrict__ c2maxp, int* __restrict__ merged)
{
  __shared__ float mv[NSPLIT * K12];
  __shared__ int   mid[NSPLIT * K12];
  const int t = blockIdx.x, tid = threadIdx.x;

  for (int e = tid; e < NSPLIT * K12; e += 64) {
    const int s = e / K12, k = e - s * K12;
    const size_t base = ((size_t)s * T_TOK + t) * 24;
    mv[e]  = p1[base + k];
    mid[e] = ((const int*)p1)[base + 12 + k];
  }
  __syncthreads();

  if (tid == 0) {
    float a8 = 0.f, a12 = 0.f;
    int sel[K12];
    for (int r = 0; r < K12; ++r) {
      float best = __builtin_inff(); int bestid = 0x7fffffff; int bs = 0;
      for (int s = 0; s < NSPLIT * K12; ++s) {
        const float dv = mv[s]; const int iv = mid[s];
        if (dv < best || (dv == best && iv < bestid)) { best = dv; bestid = iv; bs = s; }
      }
      mv[bs] = __builtin_inff();
      sel[r] = bestid;
      if (r == 7)  a8 = best;
      if (r == 11) a12 = best;
    }
    const float c2m = c2maxp[0];       // bits written via atomicMax(uint)
    const float m = MARG_K1 * sqrtf(x2g[t] * c2m) + MARG_K2;
    const int flag = !(a12 > a8 + 2.0f * m);
    for (int r = 0; r < K12; ++r) merged[(size_t)t * 13 + r] = sel[r];
    merged[(size_t)t * 13 + 12] = flag;
  }
}

// ---------------------------------------------------------------------------
// Kernel D: EXACT pass — recompute the frozen numpy arithmetic for the 12
// candidates (4-lane SSE1 chains, lane = k&3, ascending k; combine
// (l0+l2)+(l1+l3); s = fl(2xc - x2); d = -(s - c2)), exact (val,id)-lex
// top-8, out_ids, fused gather-mean. Fallback: full frozen rescan if flagged
// (flag is block-uniform, so the divergent-__syncthreads pattern is safe).
// ---------------------------------------------------------------------------
__global__ __launch_bounds__(192) void exact_gather_kernel(
    const float* __restrict__ x, const float* __restrict__ cb,
    const float* __restrict__ c2g, const float* __restrict__ x2g,
    const int* __restrict__ merged,
    float* __restrict__ out, float* __restrict__ out_ids)
{
  #pragma clang fp contract(off)
  __shared__ float lch[K12][4];
  __shared__ float dv[K12];
  __shared__ int   ssel[KSEL];
  __shared__ float fbd[192 * KSEL];
  __shared__ int   fbi[192 * KSEL];

  const int t = blockIdx.x, tid = threadIdx.x;
  const int flag = merged[(size_t)t * 13 + 12];
  const float x2t = x2g[t];
  const float* xr = x + (size_t)t * DIM;

  if (!flag) {
    if (tid < 48) {
      const int cand = tid >> 2, m = tid & 3;
      const int id = merged[(size_t)t * 13 + cand];
      const float* cr = cb + (size_t)id * DIM;
      float l = 0.f;
      for (int i = 0; i < DIM; i += 4) {
        const float tt = xr[i + m] * cr[i + m];   // fl(x*c)
        l = l + tt;                                // fl(l+t), ascending k
      }
      lch[cand][m] = l;
    }
    __syncthreads();
    if (tid < K12) {
      const float xc = (lch[tid][0] + lch[tid][2]) + (lch[tid][1] + lch[tid][3]);
      const float s  = 2.0f * xc - x2t;
      const int id = merged[(size_t)t * 13 + tid];
      dv[tid] = -(s - c2g[id]);
    }
    __syncthreads();
    if (tid == 0) {
      float lv[K12]; int li[K12];
      for (int k = 0; k < K12; ++k) { lv[k] = dv[k]; li[k] = merged[(size_t)t * 13 + k]; }
      for (int r = 0; r < KSEL; ++r) {
        float best = __builtin_inff(); int bestid = 0x7fffffff; int bs = 0;
        for (int s = 0; s < K12; ++s) {
          if (lv[s] < best || (lv[s] == best && li[s] < bestid)) {
            best = lv[s]; bestid = li[s]; bs = s;
          }
        }
        lv[bs] = __builtin_inff();
        ssel[r] = bestid;
        out_ids[(size_t)t * KSEL + r] = (float)bestid;
      }
    }
  } else {
    // ---- fallback: full frozen rescan for this token (expected never) ----
    float bdist[KSEL]; int bid[KSEL];
    #pragma unroll
    for (int i = 0; i < KSEL; ++i) { bdist[i] = __builtin_inff(); bid[i] = 0x7fffffff; }
    float bmax = __builtin_inff(); int bmaxid = 0x7fffffff; int bslot = 0;
    for (int c = tid; c < NCB; c += 192) {
      const float* cr = cb + (size_t)c * DIM;
      float l0 = 0.f, l1 = 0.f, l2 = 0.f, l3 = 0.f;
      for (int i = 0; i < DIM; i += 4) {
        float tt;
        tt = xr[i]     * cr[i];     l0 = l0 + tt;
        tt = xr[i + 1] * cr[i + 1]; l1 = l1 + tt;
        tt = xr[i + 2] * cr[i + 2]; l2 = l2 + tt;
        tt = xr[i + 3] * cr[i + 3]; l3 = l3 + tt;
      }
      const float xc = (l0 + l2) + (l1 + l3);
      const float s  = 2.0f * xc - x2t;
      const float d  = -(s - c2g[c]);
      if (d < bmax) {
        #pragma unroll
        for (int q = 0; q < KSEL; ++q)
          if (q == bslot) { bdist[q] = d; bid[q] = c; }
        bmax = bdist[0]; bmaxid = bid[0]; bslot = 0;
        #pragma unroll
        for (int q = 1; q < KSEL; ++q)
          if (bdist[q] > bmax || (bdist[q] == bmax && bid[q] > bmaxid)) {
            bmax = bdist[q]; bmaxid = bid[q]; bslot = q;
          }
      }
    }
    #pragma unroll
    for (int k = 0; k < KSEL; ++k) { fbd[tid * KSEL + k] = bdist[k]; fbi[tid * KSEL + k] = bid[k]; }
    __syncthreads();
    if (tid == 0) {
      for (int r = 0; r < KSEL; ++r) {
        float best = __builtin_inff(); int bestid = 0x7fffffff; int bs = 0;
        for (int s = 0; s < 192 * KSEL; ++s) {
          if (fbd[s] < best || (fbd[s] == best && fbi[s] < bestid)) {
            best = fbd[s]; bestid = fbi[s]; bs = s;
          }
        }
        fbd[bs] = __builtin_inff();
        ssel[r] = bestid;
        out_ids[(size_t)t * KSEL + r] = (float)bestid;
      }
    }
  }
  __syncthreads();

  // gather-mean (r ascending, as validated)
  float4 s4 = make_float4(0.f, 0.f, 0.f, 0.f);
  #pragma unroll
  for (int r = 0; r < KSEL; ++r) {
    const float4 v = *(const float4*)(cb + (size_t)ssel[r] * DIM + tid * 4);
    s4.x += v.x; s4.y += v.y; s4.z += v.z; s4.w += v.w;
  }
  s4.x *= 0.125f; s4.y *= 0.125f; s4.z *= 0.125f; s4.w *= 0.125f;
  *(float4*)(out + (size_t)t * DIM + tid * 4) = s4;
}

extern "C" void kernel_launch(void* const* d_in, const int* in_sizes, int n_in,
                              void* d_out, int out_size, void* d_ws, size_t ws_size,
                              hipStream_t stream) {
  (void)in_sizes; (void)n_in; (void)out_size; (void)ws_size;
  const float* x   = (const float*)d_in[0];
  const float* cbk = (const float*)d_in[1];
  float* out     = (float*)d_out;
  float* out_ids = out + (size_t)T_TOK * DIM;
  float* ws      = (float*)d_ws;

  // ws layout (<= 492 KB, under the established ws floor):
  float* c2buf = ws;                      // [0:8192]
  float* x2buf = ws + NCB;                // [8192:16384]
  unsigned int* c2max = (unsigned int*)(ws + 2 * NCB);   // 1 word
  int* merged = (int*)(ws + 2 * NCB + 16);               // 8192 x 13 ints
  // pass-1 scratch lives in OUT (read only by merge12, before any out write):
  float* p1out = out;                     // NSPLIT*8192*24 floats = 3.1M < 6.3M

  hipMemsetAsync(c2max, 0, 4, stream);
  sq_pairwise_kernel<<<(NCB + T_TOK) / 32, 256, 0, stream>>>(
      cbk, x, c2buf, x2buf, c2max);
  filt_topk_kernel<<<dim3(T_TOK / BT, NSPLIT), 256, 0, stream>>>(
      x, cbk, c2buf, x2buf, p1out);
  merge12_kernel<<<T_TOK, 64, 0, stream>>>(p1out, x2buf, (const float*)c2max, merged);
  exact_gather_kernel<<<T_TOK, 192, 0, stream>>>(
      x, cbk, c2buf, x2buf, merged, out, out_ids);
}